// Round 6
// baseline (269.301 us; speedup 1.0000x reference)
//
#include <hip/hip_runtime.h>
#include <stdint.h>

#define S_SCALE 11.313708498984761f
#define EPS 1e-12f

typedef __bf16 bf16x8 __attribute__((ext_vector_type(8)));
typedef float  f32x4  __attribute__((ext_vector_type(4)));

__device__ __forceinline__ f32x4 mfma16(bf16x8 a, bf16x8 b, f32x4 c) {
  return __builtin_amdgcn_mfma_f32_16x16x32_bf16(a, b, c, 0, 0, 0);
}

__device__ __forceinline__ float waveSum(float v) {
#pragma unroll
  for (int m = 32; m > 0; m >>= 1) v += __shfl_xor(v, m, 64);
  return v;
}

// async global->LDS DMA, 16B per lane, LDS dest = uniform base + lane*16
__device__ __forceinline__ void load_lds16(const float* g, float* l) {
  __builtin_amdgcn_global_load_lds(
      (const __attribute__((address_space(1))) uint32_t*)g,
      (__attribute__((address_space(3))) uint32_t*)l, 16, 0, 0);
}

// ---- ws layout (byte offsets) ----
// W bf16 [128][3072]       : [0, 786432)
// bias2 f32 [128]          : [786432, 786944)
// fn bf16 [8192][128]      : [786944, 2884096)
// Zp f32 [2][4][32][256]   : [2884096, 3146240)
// P1..P7 f32 [8192][128]   : [3146240, 32506368)
#define OFF_W    0
#define OFF_BIAS 786432
#define OFF_FN   786944
#define OFF_ZP   2884096
#define OFF_P1   3146240

// ------- fused weight (blocks 0..255): W[o][k0..k0+11] = sum_c fc1*conv_w --
// block 256: bias2[o] = fc1_w[o,:].conv_b + fc1_b[o]; zero loss.
__global__ __launch_bounds__(256) void k_fusew2(const float* __restrict__ conv_w,
                                                const float* __restrict__ fc1_w,
                                                const float* __restrict__ conv_b,
                                                const float* __restrict__ fc1_b,
                                                __bf16* __restrict__ W,
                                                float* __restrict__ bias2,
                                                float* __restrict__ loss) {
  const int t = threadIdx.x;
  const int wave = t >> 6, lane = t & 63;
  if (blockIdx.x == 256) {  // bias block
    if (t == 0) loss[0] = 0.f;
    for (int o = wave; o < 128; o += 4) {
      float p = 0.f;
#pragma unroll
      for (int c8 = 0; c8 < 8; ++c8)
        p = fmaf(fc1_w[o * 512 + c8 * 64 + lane], conv_b[c8 * 64 + lane], p);
      p = waveSum(p);
      if (lane == 0) bias2[o] = p + fc1_b[o];
    }
    return;
  }
  __shared__ float cw_s[64][12];    // [c][k-chunk of 12]
  __shared__ float fc1_s[128][65];  // [o][c], padded
  const int k0 = blockIdx.x * 12;
  const int og = t >> 1, half = t & 1;  // thread: one o, 6 k-cols
  const int kb = half * 6;
  float acc[6] = {};
  for (int cs = 0; cs < 8; ++cs) {
    const int cc = cs * 64;
    __syncthreads();
#pragma unroll
    for (int i = 0; i < 3; ++i) {
      int idx = t + 256 * i;  // 768 = 64 rows x 12 cols
      int cr = idx / 12, kk = idx - cr * 12;
      cw_s[cr][kk] = conv_w[(cc + cr) * 3072 + k0 + kk];
    }
#pragma unroll
    for (int i = 0; i < 2; ++i) {
      int idx = t + 256 * i;  // 512 tasks x 16 floats
      int o = idx >> 2, c16 = (idx & 3) * 16;
#pragma unroll
      for (int q = 0; q < 4; ++q) {
        float4 v = *(const float4*)&fc1_w[o * 512 + cc + c16 + q * 4];
        fc1_s[o][c16 + q * 4 + 0] = v.x; fc1_s[o][c16 + q * 4 + 1] = v.y;
        fc1_s[o][c16 + q * 4 + 2] = v.z; fc1_s[o][c16 + q * 4 + 3] = v.w;
      }
    }
    __syncthreads();
    for (int ci = 0; ci < 64; ++ci) {
      float fv = fc1_s[og][ci];
#pragma unroll
      for (int j = 0; j < 6; ++j)
        acc[j] = fmaf(fv, cw_s[ci][kb + j], acc[j]);
    }
  }
#pragma unroll
  for (int j = 0; j < 6; ++j)
    W[og * 3072 + k0 + kb + j] = (__bf16)acc[j];
}

// ---------------- main GEMM: pipelined global_load_lds, split-K=8 ----------
// grid (256,8) x 256 thr. Block = 32 rows x 128 cols x K=384 (6 iters BK=64).
// 8 blocks/CU: block-level overlap hides the per-barrier vmcnt(0) drain.
// A LDS XOR-swizzled in 16B chunks: phys_chunk = log_chunk ^ (row&15).

#define A_READS(BUF, AV)                                                      \
  _Pragma("unroll") for (int ks = 0; ks < 2; ++ks)                            \
      _Pragma("unroll") for (int mi = 0; mi < 2; ++mi) {                      \
    const int rb = (l15 + mi * 16) * 64;                                      \
    AV[ks][mi][0] =                                                           \
        *(const float4*)&A_lds[BUF][rb + (((ks * 8 + quad * 2) ^ l15) << 2)]; \
    AV[ks][mi][1] =                                                           \
        *(const float4*)&A_lds[BUF][rb + (((ks * 8 + quad * 2 + 1) ^ l15) << 2)]; \
  }

#define PREFETCH(IT, BUF, BB)                                                 \
  {                                                                           \
    const int kn = kbase + (IT) * 64;                                         \
    _Pragma("unroll") for (int j = 0; j < 2; ++j)                             \
        load_lds16(x + (m0 + dr[j]) * 3072 + kn + dc[j],                      \
                   &A_lds[BUF][(wave * 2 + j) * 256]);                        \
    _Pragma("unroll") for (int ks = 0; ks < 2; ++ks)                          \
        _Pragma("unroll") for (int ni = 0; ni < 2; ++ni)                      \
            BB[ks][ni] = *(const uint4*)(bp0 + ni * 49152 + (IT) * 64 + ks * 32); \
  }

#define COMPUTE(AV, BB)                                                       \
  _Pragma("unroll") for (int ks = 0; ks < 2; ++ks) {                          \
    bf16x8 afrag[2];                                                          \
    _Pragma("unroll") for (int mi = 0; mi < 2; ++mi) {                        \
      union { __bf16 h[8]; bf16x8 v; } pk;                                    \
      float4 lo = AV[ks][mi][0], hi = AV[ks][mi][1];                          \
      pk.h[0] = (__bf16)lo.x; pk.h[1] = (__bf16)lo.y;                         \
      pk.h[2] = (__bf16)lo.z; pk.h[3] = (__bf16)lo.w;                         \
      pk.h[4] = (__bf16)hi.x; pk.h[5] = (__bf16)hi.y;                         \
      pk.h[6] = (__bf16)hi.z; pk.h[7] = (__bf16)hi.w;                         \
      afrag[mi] = pk.v;                                                       \
    }                                                                         \
    _Pragma("unroll") for (int mi = 0; mi < 2; ++mi)                          \
        _Pragma("unroll") for (int ni = 0; ni < 2; ++ni)                      \
            acc[mi][ni] =                                                     \
        mfma16(afrag[mi], *(const bf16x8*)&BB[ks][ni], acc[mi][ni]);          \
  }

__global__ __launch_bounds__(256, 8) void k_gemm1(
    const float* __restrict__ x, const __bf16* __restrict__ W,
    float* __restrict__ P0, float* __restrict__ P1, float* __restrict__ P2,
    float* __restrict__ P3, float* __restrict__ P4, float* __restrict__ P5,
    float* __restrict__ P6, float* __restrict__ P7) {
  __shared__ __align__(16) float A_lds[2][32 * 64];  // 2 x 8 KB
  const int t = threadIdx.x;
  const int wave = t >> 6, lane = t & 63;
  const int l15 = lane & 15, quad = lane >> 4;
  const int m0 = blockIdx.x * 32;
  const int kbase = blockIdx.y * 384;
  float* const Ps[8] = {P0, P1, P2, P3, P4, P5, P6, P7};
  float* P = Ps[blockIdx.y];

  int dr[2], dc[2];
#pragma unroll
  for (int j = 0; j < 2; ++j) {
    int row = wave * 8 + j * 4 + (lane >> 4);
    int cl = (lane & 15) ^ (row & 15);
    dr[j] = row;
    dc[j] = cl * 4;
  }
  const __bf16* bp0 = W + (wave * 32 + l15) * 3072 + quad * 8 + kbase;

  f32x4 acc[2][2] = {{{0.f,0.f,0.f,0.f},{0.f,0.f,0.f,0.f}},
                     {{0.f,0.f,0.f,0.f},{0.f,0.f,0.f,0.f}}};
  uint4 bA[2][2], bB[2][2];
  float4 av[2][2][2];

  PREFETCH(0, 0, bA)
  for (int it2 = 0; it2 < 3; ++it2) {
    const int it = it2 * 2;
    __syncthreads();              // drains DMA(it)->buf0 + bA(it)
    A_READS(0, av)
    if (it + 1 < 6) PREFETCH(it + 1, 1, bB)
    COMPUTE(av, bA)
    __syncthreads();              // drains DMA(it+1)->buf1 + bB(it+1)
    A_READS(1, av)
    if (it + 2 < 6) PREFETCH(it + 2, 0, bA)
    COMPUTE(av, bB)
  }
#pragma unroll
  for (int mi = 0; mi < 2; ++mi)
#pragma unroll
    for (int ni = 0; ni < 2; ++ni) {
      int col = wave * 32 + ni * 16 + l15;
#pragma unroll
      for (int r = 0; r < 4; ++r) {
        int row = m0 + mi * 16 + quad * 4 + r;
        P[row * 128 + col] = acc[mi][ni][r];
      }
    }
}

// ---------------- finalize: f = sum(P0..P7)+bias, row L2-norm -> fn bf16 ---
__global__ __launch_bounds__(256) void k_fin(
    float* __restrict__ f_inout, const float* __restrict__ P1,
    const float* __restrict__ P2, const float* __restrict__ P3,
    const float* __restrict__ P4, const float* __restrict__ P5,
    const float* __restrict__ P6, const float* __restrict__ P7,
    const float* __restrict__ bias2, __bf16* __restrict__ fn) {
  const int wave = threadIdx.x >> 6, lane = threadIdx.x & 63;
  const int row = blockIdx.x * 4 + wave;
  const int i0 = row * 128 + lane, i1 = i0 + 64;
  float v0 = f_inout[i0] + P1[i0] + P2[i0] + P3[i0] + P4[i0] + P5[i0] +
             P6[i0] + P7[i0] + bias2[lane];
  float v1 = f_inout[i1] + P1[i1] + P2[i1] + P3[i1] + P4[i1] + P5[i1] +
             P6[i1] + P7[i1] + bias2[lane + 64];
  float ss = waveSum(fmaf(v0, v0, v1 * v1));
  float inv = 1.f / fmaxf(sqrtf(ss), EPS);
  f_inout[i0] = v0;
  f_inout[i1] = v1;
  fn[i0] = (__bf16)(v0 * inv);
  fn[i1] = (__bf16)(v1 * inv);
}

// ---------------- A[b] = fn_b @ fn_b^T  +  fused Z column-partials ---------
__global__ __launch_bounds__(256) void k_gemm2(const __bf16* __restrict__ fn,
                                               const float* __restrict__ d1,
                                               const float* __restrict__ d2,
                                               float* __restrict__ Aout,
                                               float* __restrict__ Zp) {
  __shared__ __align__(16) __bf16 Li[64][136];
  __shared__ __align__(16) __bf16 Lj[64][136];
  __shared__ float zred[2][4][64];
  const int t = threadIdx.x;
  const int b = blockIdx.y;
  const int ti = blockIdx.x >> 2, tj = blockIdx.x & 3;
  const int i0 = ti * 64, j0 = tj * 64;
  const int wave = t >> 6, lane = t & 63;
  const int l15 = lane & 15, quad = lane >> 4;
  const __bf16* fb = fn + b * 32768;
#pragma unroll
  for (int i = 0; i < 4; ++i) {
    int idx = t + 256 * i;
    int r = idx >> 4, c8 = (idx & 15) * 8;
    *(uint4*)&Li[r][c8] = *(const uint4*)&fb[(i0 + r) * 128 + c8];
    *(uint4*)&Lj[r][c8] = *(const uint4*)&fb[(j0 + r) * 128 + c8];
  }
  __syncthreads();
  f32x4 acc[4] = {{0.f, 0.f, 0.f, 0.f}, {0.f, 0.f, 0.f, 0.f},
                  {0.f, 0.f, 0.f, 0.f}, {0.f, 0.f, 0.f, 0.f}};
#pragma unroll
  for (int ks = 0; ks < 4; ++ks) {
    bf16x8 af = *(const bf16x8*)&Li[wave * 16 + l15][ks * 32 + quad * 8];
#pragma unroll
    for (int nt = 0; nt < 4; ++nt) {
      bf16x8 bf = *(const bf16x8*)&Lj[nt * 16 + l15][ks * 32 + quad * 8];
      acc[nt] = mfma16(af, bf, acc[nt]);
    }
  }
  const int base = b * 65536;
  float* Ab = Aout + base;
  float z1c[4] = {0.f, 0.f, 0.f, 0.f}, z2c[4] = {0.f, 0.f, 0.f, 0.f};
#pragma unroll
  for (int nt = 0; nt < 4; ++nt) {
    int gj = j0 + nt * 16 + l15;
#pragma unroll
    for (int r = 0; r < 4; ++r) {
      int gi = i0 + wave * 16 + quad * 4 + r;
      float a = acc[nt][r];
      Ab[gi * 256 + gj] = a;
      float e = __expf(fmaf(S_SCALE, a, -S_SCALE));
      if (gi != gj) {
        int idx = base + gi * 256 + gj;
        z1c[nt] = fmaf(e, d1[idx], z1c[nt]);
        z2c[nt] = fmaf(e, d2[idx], z2c[nt]);
      }
    }
  }
#pragma unroll
  for (int nt = 0; nt < 4; ++nt) {
    z1c[nt] += __shfl_xor(z1c[nt], 16, 64);
    z1c[nt] += __shfl_xor(z1c[nt], 32, 64);
    z2c[nt] += __shfl_xor(z2c[nt], 16, 64);
    z2c[nt] += __shfl_xor(z2c[nt], 32, 64);
  }
  if (quad == 0) {
#pragma unroll
    for (int nt = 0; nt < 4; ++nt) {
      zred[0][wave][nt * 16 + l15] = z1c[nt];
      zred[1][wave][nt * 16 + l15] = z2c[nt];
    }
  }
  __syncthreads();
  if (t < 128) {
    int z = t >> 6, c = t & 63;
    float s = zred[z][0][c] + zred[z][1][c] + zred[z][2][c] + zred[z][3][c];
    Zp[(z * 4 + ti) * 8192 + b * 256 + j0 + c] = s;
  }
}

// ---------------- loss = -1/8192 * sum E^2*d2[i,k]*d1[k,i]/(Z2[k]Z1[i]) ----
__global__ __launch_bounds__(256) void k_loss(const float* __restrict__ Aout,
                                              const float* __restrict__ d1,
                                              const float* __restrict__ d2,
                                              const float* __restrict__ Zp,
                                              float* __restrict__ loss) {
  __shared__ float d1s[64][65];  // d1[k][i] tile, transposed access
  __shared__ float z1s[64], z2s[64];
  __shared__ float red[4];
  const int t = threadIdx.x;
  const int b = blockIdx.y;
  const int ic = blockIdx.x >> 2, kc = blockIdx.x & 3;
  const int i0 = ic * 64, k0 = kc * 64;
  const int base = b * 65536;
  if (t < 64) {
    float s = 0.f;
#pragma unroll
    for (int p = 0; p < 4; ++p) s += Zp[p * 8192 + b * 256 + i0 + t];
    z1s[t] = 1.f / fmaxf(s, EPS);
  } else if (t < 128) {
    float s = 0.f;
#pragma unroll
    for (int p = 0; p < 4; ++p) s += Zp[(4 + p) * 8192 + b * 256 + k0 + t - 64];
    z2s[t - 64] = 1.f / fmaxf(s, EPS);
  }
#pragma unroll
  for (int ii = 0; ii < 16; ++ii) {
    int idx = t + 256 * ii;
    int kr = idx >> 6, ci = idx & 63;
    d1s[kr][ci] = d1[base + (k0 + kr) * 256 + i0 + ci];
  }
  __syncthreads();
  const int kl = t & 63, ig = t >> 6;
  float inv2 = z2s[kl];
  float accv = 0.f;
  for (int ii = 0; ii < 16; ++ii) {
    int il = ig * 16 + ii;
    int idx = base + (i0 + il) * 256 + k0 + kl;
    float a = Aout[idx];
    float e = __expf(fmaf(2.f * S_SCALE, a, -2.f * S_SCALE));
    float v = e * d2[idx] * d1s[kl][il] * z1s[il] * inv2;
    if (i0 + il != k0 + kl) accv += v;
  }
  accv = waveSum(accv);
  if ((t & 63) == 0) red[t >> 6] = accv;
  __syncthreads();
  if (t == 0) {
    float tot = red[0] + red[1] + red[2] + red[3];
    atomicAdd(loss, tot * (-1.f / 8192.f));
  }
}

extern "C" void kernel_launch(void* const* d_in, const int* in_sizes, int n_in,
                              void* d_out, int out_size, void* d_ws,
                              size_t ws_size, hipStream_t stream) {
  const float* x = (const float*)d_in[0];
  const float* conv_w = (const float*)d_in[1];
  const float* conv_b = (const float*)d_in[2];
  const float* fc1_w = (const float*)d_in[3];
  const float* fc1_b = (const float*)d_in[4];
  const float* drop1 = (const float*)d_in[5];
  const float* drop2 = (const float*)d_in[6];
  char* ws = (char*)d_ws;
  __bf16* W = (__bf16*)(ws + OFF_W);
  float* bias2 = (float*)(ws + OFF_BIAS);
  __bf16* fn = (__bf16*)(ws + OFF_FN);
  float* Zp = (float*)(ws + OFF_ZP);
  float* P1 = (float*)(ws + OFF_P1);
  float* P2 = P1 + 1048576;
  float* P3 = P2 + 1048576;
  float* P4 = P3 + 1048576;
  float* P5 = P4 + 1048576;
  float* P6 = P5 + 1048576;
  float* P7 = P6 + 1048576;
  float* f = (float*)d_out;         // [8192,128]  (doubles as P0)
  float* Aout = f + 1048576;        // [32,256,256]
  float* loss = f + 3145728;        // scalar

  k_fusew2<<<257, 256, 0, stream>>>(conv_w, fc1_w, conv_b, fc1_b, W, bias2, loss);
  k_gemm1<<<dim3(256, 8), 256, 0, stream>>>(x, W, f, P1, P2, P3, P4, P5, P6, P7);
  k_fin<<<2048, 256, 0, stream>>>(f, P1, P2, P3, P4, P5, P6, P7, bias2, fn);
  k_gemm2<<<dim3(16, 32), 256, 0, stream>>>(fn, drop1, drop2, Aout, Zp);
  k_loss<<<dim3(16, 32), 256, 0, stream>>>(Aout, drop1, drop2, Zp, loss);
}

// Round 7
// 245.168 us; speedup vs baseline: 1.0984x; 1.0984x over previous
//
#include <hip/hip_runtime.h>
#include <stdint.h>

#define S_SCALE 11.313708498984761f
#define EPS 1e-12f

typedef __bf16 bf16x8 __attribute__((ext_vector_type(8)));
typedef float  f32x4  __attribute__((ext_vector_type(4)));

__device__ __forceinline__ f32x4 mfma16(bf16x8 a, bf16x8 b, f32x4 c) {
  return __builtin_amdgcn_mfma_f32_16x16x32_bf16(a, b, c, 0, 0, 0);
}

__device__ __forceinline__ float waveSum(float v) {
#pragma unroll
  for (int m = 32; m > 0; m >>= 1) v += __shfl_xor(v, m, 64);
  return v;
}

// async global->LDS DMA, 16B per lane, LDS dest = uniform base + lane*16
__device__ __forceinline__ void load_lds16(const void* g, void* l) {
  __builtin_amdgcn_global_load_lds(
      (const __attribute__((address_space(1))) uint32_t*)g,
      (__attribute__((address_space(3))) uint32_t*)l, 16, 0, 0);
}

// ---- ws layout (byte offsets) ----
// W bf16 [128][3072]       : [0, 786432)
// bias2 f32 [128]          : [786432, 786944)
// fn bf16 [8192][128]      : [786944, 2884096)
// Zp f32 [2][4][32][256]   : [2884096, 3146240)
// P1..P7 f32 [8192][128]   : [3146240, 32506368)
#define OFF_W    0
#define OFF_BIAS 786432
#define OFF_FN   786944
#define OFF_ZP   2884096
#define OFF_P1   3146240

// ------- fused weight (blocks 0..255): W[o][k0..k0+11] = sum_c fc1*conv_w --
// block 256: bias2[o] = fc1_w[o,:].conv_b + fc1_b[o]; zero loss.
__global__ __launch_bounds__(256) void k_fusew2(const float* __restrict__ conv_w,
                                                const float* __restrict__ fc1_w,
                                                const float* __restrict__ conv_b,
                                                const float* __restrict__ fc1_b,
                                                __bf16* __restrict__ W,
                                                float* __restrict__ bias2,
                                                float* __restrict__ loss) {
  const int t = threadIdx.x;
  const int wave = t >> 6, lane = t & 63;
  if (blockIdx.x == 256) {  // bias block
    if (t == 0) loss[0] = 0.f;
    for (int o = wave; o < 128; o += 4) {
      float p = 0.f;
#pragma unroll
      for (int c8 = 0; c8 < 8; ++c8)
        p = fmaf(fc1_w[o * 512 + c8 * 64 + lane], conv_b[c8 * 64 + lane], p);
      p = waveSum(p);
      if (lane == 0) bias2[o] = p + fc1_b[o];
    }
    return;
  }
  __shared__ float cw_s[64][12];    // [c][k-chunk of 12]
  __shared__ float fc1_s[128][65];  // [o][c], padded
  const int k0 = blockIdx.x * 12;
  const int og = t >> 1, half = t & 1;  // thread: one o, 6 k-cols
  const int kb = half * 6;
  float acc[6] = {};
  for (int cs = 0; cs < 8; ++cs) {
    const int cc = cs * 64;
    __syncthreads();
#pragma unroll
    for (int i = 0; i < 3; ++i) {
      int idx = t + 256 * i;  // 768 = 64 rows x 12 cols
      int cr = idx / 12, kk = idx - cr * 12;
      cw_s[cr][kk] = conv_w[(cc + cr) * 3072 + k0 + kk];
    }
#pragma unroll
    for (int i = 0; i < 2; ++i) {
      int idx = t + 256 * i;  // 512 tasks x 16 floats
      int o = idx >> 2, c16 = (idx & 3) * 16;
#pragma unroll
      for (int q = 0; q < 4; ++q) {
        float4 v = *(const float4*)&fc1_w[o * 512 + cc + c16 + q * 4];
        fc1_s[o][c16 + q * 4 + 0] = v.x; fc1_s[o][c16 + q * 4 + 1] = v.y;
        fc1_s[o][c16 + q * 4 + 2] = v.z; fc1_s[o][c16 + q * 4 + 3] = v.w;
      }
    }
    __syncthreads();
    for (int ci = 0; ci < 64; ++ci) {
      float fv = fc1_s[og][ci];
#pragma unroll
      for (int j = 0; j < 6; ++j)
        acc[j] = fmaf(fv, cw_s[ci][kb + j], acc[j]);
    }
  }
#pragma unroll
  for (int j = 0; j < 6; ++j)
    W[og * 3072 + k0 + kb + j] = (__bf16)acc[j];
}

// ---------------- main GEMM: 128x128 tile, A+B via global_load_lds ---------
// grid (64,8) x 256 thr. Block = 128 rows x 128 cols x K=384 (6 iters BK=64).
// 2 blocks/CU. B re-read traffic cut 4x vs 32-row tiles (49 MB vs 196 MB).
// A LDS: fp32 [128][64], 16B-chunk swizzle cl^(r&15). B LDS: bf16 [128][64],
// chunk swizzle cl^(r&7). Both conflict-free (<=2-way) on frag reads.
__global__ __launch_bounds__(256, 2) void k_gemm1(
    const float* __restrict__ x, const __bf16* __restrict__ W,
    float* __restrict__ P0, float* __restrict__ P1, float* __restrict__ P2,
    float* __restrict__ P3, float* __restrict__ P4, float* __restrict__ P5,
    float* __restrict__ P6, float* __restrict__ P7) {
  __shared__ __align__(16) float As[128 * 64];    // 32 KB
  __shared__ __align__(16) __bf16 Bs[128 * 64];   // 16 KB
  const int t = threadIdx.x;
  const int wave = t >> 6, lane = t & 63;
  const int l15 = lane & 15, quad = lane >> 4;
  const int wm = wave >> 1, wn = wave & 1;  // wave tile 64x64 within 128x128
  const int m0 = blockIdx.x * 128;
  const int kbase = blockIdx.y * 384;
  float* const Ps[8] = {P0, P1, P2, P3, P4, P5, P6, P7};
  float* P = Ps[blockIdx.y];

  // A DMA: 8 insts/wave; inst j covers LDS rows (wave*8+j)*4 .. +3.
  const float* asrc[8];
  float* adst[8];
#pragma unroll
  for (int j = 0; j < 8; ++j) {
    int r = (wave * 8 + j) * 4 + (lane >> 4);
    int cl = (lane & 15) ^ (r & 15);
    asrc[j] = x + (m0 + r) * 3072 + kbase + cl * 4;
    adst[j] = &As[(wave * 8 + j) * 256];
  }
  // B DMA: 4 insts/wave; inst j covers LDS rows (wave*4+j)*8 .. +7.
  const __bf16* bsrc[4];
  __bf16* bdst[4];
#pragma unroll
  for (int j = 0; j < 4; ++j) {
    int r = (wave * 4 + j) * 8 + (lane >> 3);
    int cl = (lane & 7) ^ (r & 7);
    bsrc[j] = W + r * 3072 + kbase + cl * 8;
    bdst[j] = &Bs[(wave * 4 + j) * 512];
  }

  f32x4 acc[4][4] = {};
  for (int it = 0; it < 6; ++it) {
    __syncthreads();  // previous iter's frag reads complete
#pragma unroll
    for (int j = 0; j < 8; ++j) load_lds16(asrc[j] + it * 64, adst[j]);
#pragma unroll
    for (int j = 0; j < 4; ++j) load_lds16(bsrc[j] + it * 64, bdst[j]);
    __syncthreads();  // vmcnt(0) drain: tiles resident
#pragma unroll
    for (int ks = 0; ks < 2; ++ks) {
      bf16x8 af[4];
#pragma unroll
      for (int mi = 0; mi < 4; ++mi) {
        int r = wm * 64 + mi * 16 + l15;
        int rb = r * 64, rx = r & 15;
        float4 lo = *(const float4*)&As[rb + (((ks * 8 + quad * 2) ^ rx) << 2)];
        float4 hi = *(const float4*)&As[rb + (((ks * 8 + quad * 2 + 1) ^ rx) << 2)];
        union { __bf16 h[8]; bf16x8 v; } pk;
        pk.h[0] = (__bf16)lo.x; pk.h[1] = (__bf16)lo.y;
        pk.h[2] = (__bf16)lo.z; pk.h[3] = (__bf16)lo.w;
        pk.h[4] = (__bf16)hi.x; pk.h[5] = (__bf16)hi.y;
        pk.h[6] = (__bf16)hi.z; pk.h[7] = (__bf16)hi.w;
        af[mi] = pk.v;
      }
      bf16x8 bfr[4];
#pragma unroll
      for (int ni = 0; ni < 4; ++ni) {
        int r = wn * 64 + ni * 16 + l15;
        bfr[ni] = *(const bf16x8*)&Bs[r * 64 + (((ks * 4 + quad) ^ (r & 7)) << 3)];
      }
#pragma unroll
      for (int mi = 0; mi < 4; ++mi)
#pragma unroll
        for (int ni = 0; ni < 4; ++ni)
          acc[mi][ni] = mfma16(af[mi], bfr[ni], acc[mi][ni]);
    }
  }
#pragma unroll
  for (int mi = 0; mi < 4; ++mi)
#pragma unroll
    for (int ni = 0; ni < 4; ++ni) {
      int col = wn * 64 + ni * 16 + l15;
#pragma unroll
      for (int r = 0; r < 4; ++r) {
        int row = m0 + wm * 64 + mi * 16 + quad * 4 + r;
        P[row * 128 + col] = acc[mi][ni][r];
      }
    }
}

// ---------------- finalize: f = sum(P0..P7)+bias, row L2-norm -> fn bf16 ---
__global__ __launch_bounds__(256) void k_fin(
    float* __restrict__ f_inout, const float* __restrict__ P1,
    const float* __restrict__ P2, const float* __restrict__ P3,
    const float* __restrict__ P4, const float* __restrict__ P5,
    const float* __restrict__ P6, const float* __restrict__ P7,
    const float* __restrict__ bias2, __bf16* __restrict__ fn) {
  const int wave = threadIdx.x >> 6, lane = threadIdx.x & 63;
  const int row = blockIdx.x * 4 + wave;
  const int i0 = row * 128 + lane, i1 = i0 + 64;
  float v0 = f_inout[i0] + P1[i0] + P2[i0] + P3[i0] + P4[i0] + P5[i0] +
             P6[i0] + P7[i0] + bias2[lane];
  float v1 = f_inout[i1] + P1[i1] + P2[i1] + P3[i1] + P4[i1] + P5[i1] +
             P6[i1] + P7[i1] + bias2[lane + 64];
  float ss = waveSum(fmaf(v0, v0, v1 * v1));
  float inv = 1.f / fmaxf(sqrtf(ss), EPS);
  f_inout[i0] = v0;
  f_inout[i1] = v1;
  fn[i0] = (__bf16)(v0 * inv);
  fn[i1] = (__bf16)(v1 * inv);
}

// ---------------- A[b] = fn_b @ fn_b^T  +  fused Z column-partials ---------
__global__ __launch_bounds__(256) void k_gemm2(const __bf16* __restrict__ fn,
                                               const float* __restrict__ d1,
                                               const float* __restrict__ d2,
                                               float* __restrict__ Aout,
                                               float* __restrict__ Zp) {
  __shared__ __align__(16) __bf16 Li[64][136];
  __shared__ __align__(16) __bf16 Lj[64][136];
  __shared__ float zred[2][4][64];
  const int t = threadIdx.x;
  const int b = blockIdx.y;
  const int ti = blockIdx.x >> 2, tj = blockIdx.x & 3;
  const int i0 = ti * 64, j0 = tj * 64;
  const int wave = t >> 6, lane = t & 63;
  const int l15 = lane & 15, quad = lane >> 4;
  const __bf16* fb = fn + b * 32768;
#pragma unroll
  for (int i = 0; i < 4; ++i) {
    int idx = t + 256 * i;
    int r = idx >> 4, c8 = (idx & 15) * 8;
    *(uint4*)&Li[r][c8] = *(const uint4*)&fb[(i0 + r) * 128 + c8];
    *(uint4*)&Lj[r][c8] = *(const uint4*)&fb[(j0 + r) * 128 + c8];
  }
  __syncthreads();
  f32x4 acc[4] = {{0.f, 0.f, 0.f, 0.f}, {0.f, 0.f, 0.f, 0.f},
                  {0.f, 0.f, 0.f, 0.f}, {0.f, 0.f, 0.f, 0.f}};
#pragma unroll
  for (int ks = 0; ks < 4; ++ks) {
    bf16x8 af = *(const bf16x8*)&Li[wave * 16 + l15][ks * 32 + quad * 8];
#pragma unroll
    for (int nt = 0; nt < 4; ++nt) {
      bf16x8 bf = *(const bf16x8*)&Lj[nt * 16 + l15][ks * 32 + quad * 8];
      acc[nt] = mfma16(af, bf, acc[nt]);
    }
  }
  const int base = b * 65536;
  float* Ab = Aout + base;
  float z1c[4] = {0.f, 0.f, 0.f, 0.f}, z2c[4] = {0.f, 0.f, 0.f, 0.f};
#pragma unroll
  for (int nt = 0; nt < 4; ++nt) {
    int gj = j0 + nt * 16 + l15;
#pragma unroll
    for (int r = 0; r < 4; ++r) {
      int gi = i0 + wave * 16 + quad * 4 + r;
      float a = acc[nt][r];
      Ab[gi * 256 + gj] = a;
      float e = __expf(fmaf(S_SCALE, a, -S_SCALE));
      if (gi != gj) {
        int idx = base + gi * 256 + gj;
        z1c[nt] = fmaf(e, d1[idx], z1c[nt]);
        z2c[nt] = fmaf(e, d2[idx], z2c[nt]);
      }
    }
  }
#pragma unroll
  for (int nt = 0; nt < 4; ++nt) {
    z1c[nt] += __shfl_xor(z1c[nt], 16, 64);
    z1c[nt] += __shfl_xor(z1c[nt], 32, 64);
    z2c[nt] += __shfl_xor(z2c[nt], 16, 64);
    z2c[nt] += __shfl_xor(z2c[nt], 32, 64);
  }
  if (quad == 0) {
#pragma unroll
    for (int nt = 0; nt < 4; ++nt) {
      zred[0][wave][nt * 16 + l15] = z1c[nt];
      zred[1][wave][nt * 16 + l15] = z2c[nt];
    }
  }
  __syncthreads();
  if (t < 128) {
    int z = t >> 6, c = t & 63;
    float s = zred[z][0][c] + zred[z][1][c] + zred[z][2][c] + zred[z][3][c];
    Zp[(z * 4 + ti) * 8192 + b * 256 + j0 + c] = s;
  }
}

// ---------------- loss = -1/8192 * sum E^2*d2[i,k]*d1[k,i]/(Z2[k]Z1[i]) ----
__global__ __launch_bounds__(256) void k_loss(const float* __restrict__ Aout,
                                              const float* __restrict__ d1,
                                              const float* __restrict__ d2,
                                              const float* __restrict__ Zp,
                                              float* __restrict__ loss) {
  __shared__ float d1s[64][65];  // d1[k][i] tile, transposed access
  __shared__ float z1s[64], z2s[64];
  __shared__ float red[4];
  const int t = threadIdx.x;
  const int b = blockIdx.y;
  const int ic = blockIdx.x >> 2, kc = blockIdx.x & 3;
  const int i0 = ic * 64, k0 = kc * 64;
  const int base = b * 65536;
  if (t < 64) {
    float s = 0.f;
#pragma unroll
    for (int p = 0; p < 4; ++p) s += Zp[p * 8192 + b * 256 + i0 + t];
    z1s[t] = 1.f / fmaxf(s, EPS);
  } else if (t < 128) {
    float s = 0.f;
#pragma unroll
    for (int p = 0; p < 4; ++p) s += Zp[(4 + p) * 8192 + b * 256 + k0 + t - 64];
    z2s[t - 64] = 1.f / fmaxf(s, EPS);
  }
#pragma unroll
  for (int ii = 0; ii < 16; ++ii) {
    int idx = t + 256 * ii;
    int kr = idx >> 6, ci = idx & 63;
    d1s[kr][ci] = d1[base + (k0 + kr) * 256 + i0 + ci];
  }
  __syncthreads();
  const int kl = t & 63, ig = t >> 6;
  float inv2 = z2s[kl];
  float accv = 0.f;
  for (int ii = 0; ii < 16; ++ii) {
    int il = ig * 16 + ii;
    int idx = base + (i0 + il) * 256 + k0 + kl;
    float a = Aout[idx];
    float e = __expf(fmaf(2.f * S_SCALE, a, -2.f * S_SCALE));
    float v = e * d2[idx] * d1s[kl][il] * z1s[il] * inv2;
    if (i0 + il != k0 + kl) accv += v;
  }
  accv = waveSum(accv);
  if ((t & 63) == 0) red[t >> 6] = accv;
  __syncthreads();
  if (t == 0) {
    float tot = red[0] + red[1] + red[2] + red[3];
    atomicAdd(loss, tot * (-1.f / 8192.f));
  }
}

extern "C" void kernel_launch(void* const* d_in, const int* in_sizes, int n_in,
                              void* d_out, int out_size, void* d_ws,
                              size_t ws_size, hipStream_t stream) {
  const float* x = (const float*)d_in[0];
  const float* conv_w = (const float*)d_in[1];
  const float* conv_b = (const float*)d_in[2];
  const float* fc1_w = (const float*)d_in[3];
  const float* fc1_b = (const float*)d_in[4];
  const float* drop1 = (const float*)d_in[5];
  const float* drop2 = (const float*)d_in[6];
  char* ws = (char*)d_ws;
  __bf16* W = (__bf16*)(ws + OFF_W);
  float* bias2 = (float*)(ws + OFF_BIAS);
  __bf16* fn = (__bf16*)(ws + OFF_FN);
  float* Zp = (float*)(ws + OFF_ZP);
  float* P1 = (float*)(ws + OFF_P1);
  float* P2 = P1 + 1048576;
  float* P3 = P2 + 1048576;
  float* P4 = P3 + 1048576;
  float* P5 = P4 + 1048576;
  float* P6 = P5 + 1048576;
  float* P7 = P6 + 1048576;
  float* f = (float*)d_out;         // [8192,128]  (doubles as P0)
  float* Aout = f + 1048576;        // [32,256,256]
  float* loss = f + 3145728;        // scalar

  k_fusew2<<<257, 256, 0, stream>>>(conv_w, fc1_w, conv_b, fc1_b, W, bias2, loss);
  k_gemm1<<<dim3(64, 8), 256, 0, stream>>>(x, W, f, P1, P2, P3, P4, P5, P6, P7);
  k_fin<<<2048, 256, 0, stream>>>(f, P1, P2, P3, P4, P5, P6, P7, bias2, fn);
  k_gemm2<<<dim3(16, 32), 256, 0, stream>>>(fn, drop1, drop2, Aout, Zp);
  k_loss<<<dim3(16, 32), 256, 0, stream>>>(Aout, drop1, drop2, Zp, loss);
}